// Round 1
// baseline (69.533 us; speedup 1.0000x reference)
//
#include <hip/hip_runtime.h>
#include <hip/hip_bf16.h>

// Analytical collapse of the reference:
//   hierarchy is deterministic: slot levels [0,1,1,1,1,2,2,2,2,3,3,3],
//   anchors [0,0,0,0,0,1,1,1,1,5,5,5]; every atom index n*12+k is valid and
//   each bead row writes only its own 12 atoms, so nanmean over beads is the
//   identity on the single non-NaN entry per atom column.
//
//   rel[k]  = node_output[n,3k:3k+3]/(||.||+1e-5) * bond_lengths[type,k]
//   pos[0]  = bead_pos
//   pos[k]  = bead_pos + rel[k]                     (k=1..4)
//   pos[k]  = bead_pos + rel[1] + rel[k]            (k=5..8)
//   pos[k]  = bead_pos + rel[1] + rel[5] + rel[k]   (k=9..11)
//   shift   = sum_k w[k]*pos[k] - bead_pos
//   out[n*12+k] = pos[k] - shift
//
// One thread per bead; 1500 threads total. Latency-bound.

#define N_BEADS 1500
#define K_SLOTS 12

__global__ __launch_bounds__(256) void hier_recon_kernel(
    const float* __restrict__ node_output,   // (N, 36)
    const float* __restrict__ bead_pos,      // (N, 3)
    const float* __restrict__ weights,       // (N, 12)
    const float* __restrict__ bond_lengths,  // (33, 12)
    const int*   __restrict__ bead_types,    // (N,)
    float*       __restrict__ out)           // (N*12, 3)
{
    int n = blockIdx.x * blockDim.x + threadIdx.x;
    if (n >= N_BEADS) return;

    // --- load node_output row: 36 floats = 9 float4 (144B row, 16B aligned)
    float4 nov[9];
    const float4* src = (const float4*)(node_output + n * 36);
#pragma unroll
    for (int i = 0; i < 9; ++i) nov[i] = src[i];
    const float* nf = (const float*)nov;

    const int t = bead_types[n];
    const float* blp = bond_lengths + t * K_SLOTS;
    const float* wp  = weights + n * K_SLOTS;

    float bl[K_SLOTS], w[K_SLOTS];
#pragma unroll
    for (int k = 0; k < K_SLOTS; ++k) { bl[k] = blp[k]; w[k] = wp[k]; }

    const float px = bead_pos[n * 3 + 0];
    const float py = bead_pos[n * 3 + 1];
    const float pz = bead_pos[n * 3 + 2];

    // --- rel vectors
    float rx[K_SLOTS], ry[K_SLOTS], rz[K_SLOTS];
#pragma unroll
    for (int k = 0; k < K_SLOTS; ++k) {
        float x = nf[3 * k + 0];
        float y = nf[3 * k + 1];
        float z = nf[3 * k + 2];
        float s = bl[k] / (sqrtf(x * x + y * y + z * z) + 1e-5f);
        rx[k] = x * s; ry[k] = y * s; rz[k] = z * s;
    }

    // --- chained positions
    float posx[K_SLOTS], posy[K_SLOTS], posz[K_SLOTS];
    posx[0] = px; posy[0] = py; posz[0] = pz;
#pragma unroll
    for (int k = 1; k <= 4; ++k) {
        posx[k] = px + rx[k]; posy[k] = py + ry[k]; posz[k] = pz + rz[k];
    }
#pragma unroll
    for (int k = 5; k <= 8; ++k) {
        posx[k] = px + rx[1] + rx[k];
        posy[k] = py + ry[1] + ry[k];
        posz[k] = pz + rz[1] + rz[k];
    }
#pragma unroll
    for (int k = 9; k <= 11; ++k) {
        posx[k] = px + rx[1] + rx[5] + rx[k];
        posy[k] = py + ry[1] + ry[5] + ry[k];
        posz[k] = pz + rz[1] + rz[5] + rz[k];
    }

    // --- center of mass & shift
    float cmx = 0.f, cmy = 0.f, cmz = 0.f;
#pragma unroll
    for (int k = 0; k < K_SLOTS; ++k) {
        cmx += w[k] * posx[k];
        cmy += w[k] * posy[k];
        cmz += w[k] * posz[k];
    }
    const float sx = cmx - px, sy = cmy - py, sz = cmz - pz;

    // --- pack 36 output floats, write as 9 float4 (row offset 144B aligned)
    float obuf[36];
#pragma unroll
    for (int k = 0; k < K_SLOTS; ++k) {
        obuf[3 * k + 0] = posx[k] - sx;
        obuf[3 * k + 1] = posy[k] - sy;
        obuf[3 * k + 2] = posz[k] - sz;
    }
    float4* dst = (float4*)(out + n * 36);
    const float4* ob = (const float4*)obuf;
#pragma unroll
    for (int i = 0; i < 9; ++i) dst[i] = ob[i];
}

extern "C" void kernel_launch(void* const* d_in, const int* in_sizes, int n_in,
                              void* d_out, int out_size, void* d_ws, size_t ws_size,
                              hipStream_t stream) {
    const float* node_output  = (const float*)d_in[0];  // 54000
    const float* bead_pos     = (const float*)d_in[1];  // 4500
    const float* weights      = (const float*)d_in[2];  // 18000
    const float* bond_lengths = (const float*)d_in[3];  // 396
    const int*   bead_types   = (const int*)d_in[4];    // 1500

    const int block = 256;
    const int grid = (N_BEADS + block - 1) / block;  // 6
    hier_recon_kernel<<<grid, block, 0, stream>>>(
        node_output, bead_pos, weights, bond_lengths, bead_types,
        (float*)d_out);
}